// Round 3
// baseline (679.690 us; speedup 1.0000x reference)
//
#include <hip/hip_runtime.h>
#include <stdint.h>

typedef unsigned short u16;
typedef __bf16 bf16x8 __attribute__((ext_vector_type(8)));
typedef u16   u16x8  __attribute__((ext_vector_type(8)));
typedef float f32x4  __attribute__((ext_vector_type(4)));

#define GLOBAL_AS __attribute__((address_space(1)))
#define LDS_AS __attribute__((address_space(3)))

#define MDIM 8192
#define NDIM 4096
#define KDIM 4096
#define RDIM 16

#define BM 128
#define BN 128
#define BK 64

// ws layout (path A): [x_bf16 64MB][W_bf16 32MB][A_bf16 128KB][t fp32 512KB]
#define XBF_OFF 0
#define WBF_OFF (MDIM * KDIM * 2)                       // 67108864
#define ABF_OFF (WBF_OFF + NDIM * KDIM * 2)             // 100663296
#define T_OFF   (ABF_OFF + RDIM * KDIM * 2)             // 100794368
#define WS_NEED ((size_t)T_OFF + MDIM * RDIM * 4)       // 101318656

__device__ __forceinline__ u16 f2bf(float f) {
    union { float f; uint32_t u; } un;
    un.f = f;
    uint32_t u = un.u;
    u += 0x7FFFu + ((u >> 16) & 1u);   // round-to-nearest-even
    return (u16)(u >> 16);
}

// ---------------------------------------------------------------------------
// fp32 -> bf16 convert, 8 elements per thread-iteration (grid-stride)
// ---------------------------------------------------------------------------
__global__ __launch_bounds__(256) void cvt_kernel(
        const float* __restrict__ src, u16* __restrict__ dst, int n8) {
    int i = blockIdx.x * blockDim.x + threadIdx.x;
    const int stride = gridDim.x * blockDim.x;
    for (; i < n8; i += stride) {
        const float* p = src + (size_t)i * 8;
        f32x4 a = *(const f32x4*)p;
        f32x4 b = *(const f32x4*)(p + 4);
        u16x8 o;
        o[0] = f2bf(a[0]); o[1] = f2bf(a[1]); o[2] = f2bf(a[2]); o[3] = f2bf(a[3]);
        o[4] = f2bf(b[0]); o[5] = f2bf(b[1]); o[6] = f2bf(b[2]); o[7] = f2bf(b[3]);
        *(u16x8*)(dst + (size_t)i * 8) = o;
    }
}

// ---------------------------------------------------------------------------
// Kernel 1 (path A): t[n][r] = sum_i x[n,i]*A[r,i], bf16 in / fp32 out
// ---------------------------------------------------------------------------
__global__ __launch_bounds__(256) void lora_t_kernel(
        const u16* __restrict__ x, const u16* __restrict__ A,
        float* __restrict__ t) {
    const int wave = threadIdx.x >> 6;
    const int lane = threadIdx.x & 63;
    const int rl   = lane & 15;
    const int quad = lane >> 4;
    const int m0   = (blockIdx.x * 4 + wave) * 16;

    const u16* xp = x + (size_t)(m0 + rl) * KDIM + quad * 8;  // A-op: x[m][k]
    const u16* ap = A + (size_t)rl * KDIM + quad * 8;         // B-op: B[k][n]=A[n][k]

    f32x4 acc = {0.f, 0.f, 0.f, 0.f};
#pragma unroll 8
    for (int k = 0; k < KDIM; k += 32) {
        bf16x8 av = *(const bf16x8*)(xp + k);
        bf16x8 bv = *(const bf16x8*)(ap + k);
        acc = __builtin_amdgcn_mfma_f32_16x16x32_bf16(av, bv, acc, 0, 0, 0);
    }
    const int orow = m0 + quad * 4;   // C/D: col=lane&15, row=quad*4+v
#pragma unroll
    for (int v = 0; v < 4; ++v)
        t[(size_t)(orow + v) * RDIM + rl] = acc[v];
}

// Kernel 1 (path B): same, fp32 inputs converted inline
__global__ __launch_bounds__(256) void lora_t_inline_kernel(
        const float* __restrict__ x, const float* __restrict__ A,
        float* __restrict__ t) {
    const int wave = threadIdx.x >> 6;
    const int lane = threadIdx.x & 63;
    const int rl   = lane & 15;
    const int quad = lane >> 4;
    const int m0   = (blockIdx.x * 4 + wave) * 16;

    const float* xp = x + (size_t)(m0 + rl) * KDIM + quad * 8;
    const float* ap = A + (size_t)rl * KDIM + quad * 8;

    f32x4 acc = {0.f, 0.f, 0.f, 0.f};
    for (int k = 0; k < KDIM; k += 32) {
        f32x4 a0 = *(const f32x4*)(xp + k), a1 = *(const f32x4*)(xp + k + 4);
        f32x4 b0 = *(const f32x4*)(ap + k), b1 = *(const f32x4*)(ap + k + 4);
        u16x8 av, bv;
#pragma unroll
        for (int j = 0; j < 4; ++j) {
            av[j] = f2bf(a0[j]); av[j + 4] = f2bf(a1[j]);
            bv[j] = f2bf(b0[j]); bv[j + 4] = f2bf(b1[j]);
        }
        acc = __builtin_amdgcn_mfma_f32_16x16x32_bf16(
            (bf16x8)av, (bf16x8)bv, acc, 0, 0, 0);
    }
    const int orow = m0 + quad * 4;
#pragma unroll
    for (int v = 0; v < 4; ++v)
        t[(size_t)(orow + v) * RDIM + rl] = acc[v];
}

// ---------------------------------------------------------------------------
// Shared ext-tile staging: sAe = [2t | 1.0 | 0...], sBe = [Bl | b | 0...]
// (k-extension 4096..4127 folding LoRA + bias into one MFMA K-step)
// ---------------------------------------------------------------------------
__device__ __forceinline__ void stage_ext(
        int tid, int bm, int bn,
        const float* __restrict__ t, const float* __restrict__ bias,
        const float* __restrict__ Bl, u16* sAe, u16* sBe) {
    if (tid < 128) {
        const int r = tid;
        const float* tp = t + (size_t)(bm + r) * RDIM;
        u16* d = sAe + r * 32;
#pragma unroll
        for (int j = 0; j < RDIM; ++j) d[j] = f2bf(2.0f * tp[j]);
        d[16] = 0x3F80;                                  // 1.0 bf16
#pragma unroll
        for (int j = 17; j < 32; ++j) d[j] = 0;
    } else {
        const int r = tid - 128;
        const float* bp = Bl + (size_t)(bn + r) * RDIM;  // Bl (4096,16) fp32
        u16* d = sBe + r * 32;
#pragma unroll
        for (int j = 0; j < RDIM; ++j) d[j] = f2bf(bp[j]);
        d[16] = f2bf(bias[bn + r]);
#pragma unroll
        for (int j = 17; j < 32; ++j) d[j] = 0;
    }
}

// ---------------------------------------------------------------------------
// Kernel 2 (path A): m97-style. bf16 x/W from ws, global_load_lds width=16.
// out = x @ W^T + bias + 2*(t @ Bl^T); fp32 store.
// ---------------------------------------------------------------------------
__global__ __launch_bounds__(256) void gemm_lora_kernel(
        const u16* __restrict__ x, const u16* __restrict__ W,
        const float* __restrict__ bias, const float* __restrict__ Bl,
        const float* __restrict__ t, float* __restrict__ out) {
    __shared__ __align__(16) u16 sA[BM * BK];   // 16 KB
    __shared__ __align__(16) u16 sB[BN * BK];   // 16 KB
    __shared__ __align__(16) u16 sAe[BM * 32];  // 8 KB
    __shared__ __align__(16) u16 sBe[BN * 32];  // 8 KB

    const int tid  = threadIdx.x;
    const int lane = tid & 63;
    const int wave = tid >> 6;
    const int wm   = wave >> 1;
    const int wn   = wave & 1;
    const int rl   = lane & 15;
    const int quad = lane >> 4;
    const int bm   = blockIdx.y * BM;
    const int bn   = blockIdx.x * BN;

    stage_ext(tid, bm, bn, t, bias, Bl, sAe, sBe);

    const u16* gA = x + (size_t)bm * KDIM;
    const u16* gB = W + (size_t)bn * KDIM;

    f32x4 acc[4][4];
#pragma unroll
    for (int i = 0; i < 4; ++i)
#pragma unroll
        for (int j = 0; j < 4; ++j)
            acc[i][j] = (f32x4){0.f, 0.f, 0.f, 0.f};

    for (int kt = 0; kt < KDIM; kt += BK) {
        // chunk c = q*256+tid: row=c>>3, kc=c&7; lds offset c*16B
        // within a wave: lds = uniform(q,wave) + lane*16  (wave-uniform rule OK)
#pragma unroll
        for (int q = 0; q < 4; ++q) {
            const int c   = q * 256 + tid;
            const int row = c >> 3;
            const int kc  = c & 7;
            __builtin_amdgcn_global_load_lds(
                (const GLOBAL_AS uint32_t*)(gA + (size_t)row * KDIM + kt + kc * 8),
                (LDS_AS uint32_t*)(sA + c * 8), 16, 0, 0);
            __builtin_amdgcn_global_load_lds(
                (const GLOBAL_AS uint32_t*)(gB + (size_t)row * KDIM + kt + kc * 8),
                (LDS_AS uint32_t*)(sB + c * 8), 16, 0, 0);
        }
        __syncthreads();   // drains vmcnt(0): tiles resident

#pragma unroll
        for (int kk = 0; kk < 2; ++kk) {
            const int ko = kk * 32 + quad * 8;
            bf16x8 af[4], bfv[4];
#pragma unroll
            for (int i = 0; i < 4; ++i) {
                af[i]  = *(const bf16x8*)(sA + (wm * 64 + i * 16 + rl) * BK + ko);
                bfv[i] = *(const bf16x8*)(sB + (wn * 64 + i * 16 + rl) * BK + ko);
            }
#pragma unroll
            for (int i = 0; i < 4; ++i)
#pragma unroll
                for (int j = 0; j < 4; ++j)
                    acc[i][j] = __builtin_amdgcn_mfma_f32_16x16x32_bf16(
                        af[i], bfv[j], acc[i][j], 0, 0, 0);
        }
        __syncthreads();   // all waves done reading before next overwrite
    }

    // extension K-step (bias + LoRA)
    {
        const int ko = quad * 8;
        bf16x8 af[4], bfv[4];
#pragma unroll
        for (int i = 0; i < 4; ++i) {
            af[i]  = *(const bf16x8*)(sAe + (wm * 64 + i * 16 + rl) * 32 + ko);
            bfv[i] = *(const bf16x8*)(sBe + (wn * 64 + i * 16 + rl) * 32 + ko);
        }
#pragma unroll
        for (int i = 0; i < 4; ++i)
#pragma unroll
            for (int j = 0; j < 4; ++j)
                acc[i][j] = __builtin_amdgcn_mfma_f32_16x16x32_bf16(
                    af[i], bfv[j], acc[i][j], 0, 0, 0);
    }

    // store fp32: C/D col=lane&15, row=quad*4+v
#pragma unroll
    for (int i = 0; i < 4; ++i) {
        const int grow = bm + wm * 64 + i * 16 + quad * 4;
#pragma unroll
        for (int j = 0; j < 4; ++j) {
            const int gcol = bn + wn * 64 + j * 16 + rl;
#pragma unroll
            for (int v = 0; v < 4; ++v)
                out[(size_t)(grow + v) * NDIM + gcol] = acc[i][j][v];
        }
    }
}

// ---------------------------------------------------------------------------
// Kernel 2 (path B fallback): fp32 x/W, inline cvt, register->LDS staging
// ---------------------------------------------------------------------------
__global__ __launch_bounds__(256) void gemm_lora_inline_kernel(
        const float* __restrict__ x, const float* __restrict__ W,
        const float* __restrict__ bias, const float* __restrict__ Bl,
        const float* __restrict__ t, float* __restrict__ out) {
    __shared__ __align__(16) u16 sA[BM * BK];
    __shared__ __align__(16) u16 sB[BN * BK];
    __shared__ __align__(16) u16 sAe[BM * 32];
    __shared__ __align__(16) u16 sBe[BN * 32];

    const int tid  = threadIdx.x;
    const int lane = tid & 63;
    const int wave = tid >> 6;
    const int wm   = wave >> 1;
    const int wn   = wave & 1;
    const int rl   = lane & 15;
    const int quad = lane >> 4;
    const int bm   = blockIdx.y * BM;
    const int bn   = blockIdx.x * BN;

    stage_ext(tid, bm, bn, t, bias, Bl, sAe, sBe);

    const float* gA = x + (size_t)bm * KDIM;
    const float* gB = W + (size_t)bn * KDIM;

    const int c0   = tid;
    const int row0 = c0 >> 3;
    const int kc0  = c0 & 7;

    f32x4 acc[4][4];
#pragma unroll
    for (int i = 0; i < 4; ++i)
#pragma unroll
        for (int j = 0; j < 4; ++j)
            acc[i][j] = (f32x4){0.f, 0.f, 0.f, 0.f};

    for (int kt = 0; kt < KDIM; kt += BK) {
        u16x8 ra[4], rb[4];
#pragma unroll
        for (int q = 0; q < 4; ++q) {
            const size_t base = (size_t)(q * 32 + row0) * KDIM + kt + kc0 * 8;
            f32x4 a0 = *(const f32x4*)(gA + base), a1 = *(const f32x4*)(gA + base + 4);
            f32x4 b0 = *(const f32x4*)(gB + base), b1 = *(const f32x4*)(gB + base + 4);
#pragma unroll
            for (int j = 0; j < 4; ++j) {
                ra[q][j] = f2bf(a0[j]); ra[q][j + 4] = f2bf(a1[j]);
                rb[q][j] = f2bf(b0[j]); rb[q][j + 4] = f2bf(b1[j]);
            }
        }
        __syncthreads();
#pragma unroll
        for (int q = 0; q < 4; ++q) {
            const int c = q * 256 + c0;
            *(u16x8*)(sA + c * 8) = ra[q];
            *(u16x8*)(sB + c * 8) = rb[q];
        }
        __syncthreads();

#pragma unroll
        for (int kk = 0; kk < 2; ++kk) {
            const int ko = kk * 32 + quad * 8;
            bf16x8 af[4], bfv[4];
#pragma unroll
            for (int i = 0; i < 4; ++i) {
                af[i]  = *(const bf16x8*)(sA + (wm * 64 + i * 16 + rl) * BK + ko);
                bfv[i] = *(const bf16x8*)(sB + (wn * 64 + i * 16 + rl) * BK + ko);
            }
#pragma unroll
            for (int i = 0; i < 4; ++i)
#pragma unroll
                for (int j = 0; j < 4; ++j)
                    acc[i][j] = __builtin_amdgcn_mfma_f32_16x16x32_bf16(
                        af[i], bfv[j], acc[i][j], 0, 0, 0);
        }
    }

    {
        const int ko = quad * 8;
        bf16x8 af[4], bfv[4];
#pragma unroll
        for (int i = 0; i < 4; ++i) {
            af[i]  = *(const bf16x8*)(sAe + (wm * 64 + i * 16 + rl) * 32 + ko);
            bfv[i] = *(const bf16x8*)(sBe + (wn * 64 + i * 16 + rl) * 32 + ko);
        }
#pragma unroll
        for (int i = 0; i < 4; ++i)
#pragma unroll
            for (int j = 0; j < 4; ++j)
                acc[i][j] = __builtin_amdgcn_mfma_f32_16x16x32_bf16(
                    af[i], bfv[j], acc[i][j], 0, 0, 0);
    }

#pragma unroll
    for (int i = 0; i < 4; ++i) {
        const int grow = bm + wm * 64 + i * 16 + quad * 4;
#pragma unroll
        for (int j = 0; j < 4; ++j) {
            const int gcol = bn + wn * 64 + j * 16 + rl;
#pragma unroll
            for (int v = 0; v < 4; ++v)
                out[(size_t)(grow + v) * NDIM + gcol] = acc[i][j][v];
        }
    }
}

// ---------------------------------------------------------------------------
extern "C" void kernel_launch(void* const* d_in, const int* in_sizes, int n_in,
                              void* d_out, int out_size, void* d_ws, size_t ws_size,
                              hipStream_t stream) {
    const float* x  = (const float*)d_in[0];  // (8192, 4096) fp32
    const float* W  = (const float*)d_in[1];  // (4096, 4096) fp32
    const float* b  = (const float*)d_in[2];  // (4096,)      fp32
    const float* A  = (const float*)d_in[3];  // (16, 4096)   fp32
    const float* Bl = (const float*)d_in[4];  // (4096, 16)   fp32
    float* out = (float*)d_out;               // (8192, 4096) fp32
    char* ws = (char*)d_ws;

    dim3 grid(NDIM / BN, MDIM / BM);  // (32, 64)

    if (ws_size >= WS_NEED) {
        // Path A: convert x/W/A to bf16 in ws, then m97-style GEMM
        u16*   xbf = (u16*)(ws + XBF_OFF);
        u16*   Wbf = (u16*)(ws + WBF_OFF);
        u16*   Abf = (u16*)(ws + ABF_OFF);
        float* t   = (float*)(ws + T_OFF);

        cvt_kernel<<<4096, 256, 0, stream>>>(x, xbf, MDIM * KDIM / 8);
        cvt_kernel<<<4096, 256, 0, stream>>>(W, Wbf, NDIM * KDIM / 8);
        cvt_kernel<<<32,   256, 0, stream>>>(A, Abf, RDIM * KDIM / 8);
        lora_t_kernel<<<128, 256, 0, stream>>>(xbf, Abf, t);
        gemm_lora_kernel<<<grid, 256, 0, stream>>>(xbf, Wbf, b, Bl, t, out);
    } else {
        // Path B: inline-converting fallback; only t (512 KB) in ws
        float* t = (float*)ws;
        lora_t_inline_kernel<<<128, 256, 0, stream>>>(x, A, t);
        gemm_lora_inline_kernel<<<grid, 256, 0, stream>>>(x, W, b, Bl, t, out);
    }
}

// Round 4
// 641.069 us; speedup vs baseline: 1.0602x; 1.0602x over previous
//
#include <hip/hip_runtime.h>
#include <stdint.h>

typedef unsigned short u16;
typedef __bf16 bf16x8 __attribute__((ext_vector_type(8)));
typedef u16   u16x8  __attribute__((ext_vector_type(8)));
typedef float f32x4  __attribute__((ext_vector_type(4)));

#define GLOBAL_AS __attribute__((address_space(1)))
#define LDS_AS __attribute__((address_space(3)))

#define MDIM 8192
#define NDIM 4096
#define KDIM 4096
#define RDIM 16

#define BM 128
#define BN 128
#define BK 64
#define EXTS 40   // ext-tile row stride in u16 (padded: 80 B -> 2-way bank aliasing)

// ws layout (path A): [x_bf16 64MB][W_bf16 32MB][A_bf16 128KB][t fp32 512KB]
#define XBF_OFF 0
#define WBF_OFF (MDIM * KDIM * 2)
#define ABF_OFF (WBF_OFF + NDIM * KDIM * 2)
#define T_OFF   (ABF_OFF + RDIM * KDIM * 2)
#define WS_NEED ((size_t)T_OFF + MDIM * RDIM * 4)

#define XN8 (MDIM * KDIM / 8)
#define WN8 (NDIM * KDIM / 8)
#define AN8 (RDIM * KDIM / 8)

__device__ __forceinline__ u16 f2bf(float f) {
    union { float f; uint32_t u; } un;
    un.f = f;
    uint32_t u = un.u;
    u += 0x7FFFu + ((u >> 16) & 1u);   // round-to-nearest-even
    return (u16)(u >> 16);
}

__device__ __forceinline__ void cvt8(const float* __restrict__ p, u16* __restrict__ d) {
    f32x4 a = *(const f32x4*)p;
    f32x4 b = *(const f32x4*)(p + 4);
    u16x8 o;
    o[0] = f2bf(a[0]); o[1] = f2bf(a[1]); o[2] = f2bf(a[2]); o[3] = f2bf(a[3]);
    o[4] = f2bf(b[0]); o[5] = f2bf(b[1]); o[6] = f2bf(b[2]); o[7] = f2bf(b[3]);
    *(u16x8*)d = o;
}

// ---------------------------------------------------------------------------
// fused fp32->bf16 convert for x, W, A (one launch)
// ---------------------------------------------------------------------------
__global__ __launch_bounds__(256) void cvt_all_kernel(
        const float* __restrict__ x, const float* __restrict__ W,
        const float* __restrict__ A,
        u16* __restrict__ xbf, u16* __restrict__ Wbf, u16* __restrict__ Abf) {
    const int total = XN8 + WN8 + AN8;
    int i = blockIdx.x * blockDim.x + threadIdx.x;
    const int stride = gridDim.x * blockDim.x;
    for (; i < total; i += stride) {
        if (i < XN8) {
            cvt8(x + (size_t)i * 8, xbf + (size_t)i * 8);
        } else if (i < XN8 + WN8) {
            const int j = i - XN8;
            cvt8(W + (size_t)j * 8, Wbf + (size_t)j * 8);
        } else {
            const int j = i - XN8 - WN8;
            cvt8(A + (size_t)j * 8, Abf + (size_t)j * 8);
        }
    }
}

// ---------------------------------------------------------------------------
// Kernel 1: t[n][r] = sum_i x[n,i]*A[r,i], bf16 in / fp32 out
// ---------------------------------------------------------------------------
__global__ __launch_bounds__(256) void lora_t_kernel(
        const u16* __restrict__ x, const u16* __restrict__ A,
        float* __restrict__ t) {
    const int wave = threadIdx.x >> 6;
    const int lane = threadIdx.x & 63;
    const int rl   = lane & 15;
    const int quad = lane >> 4;
    const int m0   = (blockIdx.x * 4 + wave) * 16;

    const u16* xp = x + (size_t)(m0 + rl) * KDIM + quad * 8;  // A-op: x[m][k]
    const u16* ap = A + (size_t)rl * KDIM + quad * 8;         // B-op: B[k][n]=A[n][k]

    f32x4 acc = {0.f, 0.f, 0.f, 0.f};
#pragma unroll 8
    for (int k = 0; k < KDIM; k += 32) {
        bf16x8 av = *(const bf16x8*)(xp + k);
        bf16x8 bv = *(const bf16x8*)(ap + k);
        acc = __builtin_amdgcn_mfma_f32_16x16x32_bf16(av, bv, acc, 0, 0, 0);
    }
    const int orow = m0 + quad * 4;   // C/D: col=lane&15, row=quad*4+v
#pragma unroll
    for (int v = 0; v < 4; ++v)
        t[(size_t)(orow + v) * RDIM + rl] = acc[v];
}

// Kernel 1 (path B): fp32 inputs, inline cvt
__global__ __launch_bounds__(256) void lora_t_inline_kernel(
        const float* __restrict__ x, const float* __restrict__ A,
        float* __restrict__ t) {
    const int wave = threadIdx.x >> 6;
    const int lane = threadIdx.x & 63;
    const int rl   = lane & 15;
    const int quad = lane >> 4;
    const int m0   = (blockIdx.x * 4 + wave) * 16;

    const float* xp = x + (size_t)(m0 + rl) * KDIM + quad * 8;
    const float* ap = A + (size_t)rl * KDIM + quad * 8;

    f32x4 acc = {0.f, 0.f, 0.f, 0.f};
    for (int k = 0; k < KDIM; k += 32) {
        f32x4 a0 = *(const f32x4*)(xp + k), a1 = *(const f32x4*)(xp + k + 4);
        f32x4 b0 = *(const f32x4*)(ap + k), b1 = *(const f32x4*)(ap + k + 4);
        u16x8 av, bv;
#pragma unroll
        for (int j = 0; j < 4; ++j) {
            av[j] = f2bf(a0[j]); av[j + 4] = f2bf(a1[j]);
            bv[j] = f2bf(b0[j]); bv[j + 4] = f2bf(b1[j]);
        }
        acc = __builtin_amdgcn_mfma_f32_16x16x32_bf16(
            (bf16x8)av, (bf16x8)bv, acc, 0, 0, 0);
    }
    const int orow = m0 + quad * 4;
#pragma unroll
    for (int v = 0; v < 4; ++v)
        t[(size_t)(orow + v) * RDIM + rl] = acc[v];
}

// ---------------------------------------------------------------------------
// Ext-tile staging (stride EXTS): eA = [2t | 1.0 | 0...], eB = [Bl | b | 0...]
// ---------------------------------------------------------------------------
__device__ __forceinline__ void stage_ext(
        int tid, int bm, int bn,
        const float* __restrict__ t, const float* __restrict__ bias,
        const float* __restrict__ Bl, u16* eA, u16* eB) {
    if (tid < 128) {
        const int r = tid;
        const float* tp = t + (size_t)(bm + r) * RDIM;
        u16* d = eA + r * EXTS;
#pragma unroll
        for (int j = 0; j < RDIM; ++j) d[j] = f2bf(2.0f * tp[j]);
        d[16] = 0x3F80;                                  // 1.0 bf16
#pragma unroll
        for (int j = 17; j < 32; ++j) d[j] = 0;
    } else {
        const int r = tid - 128;
        const float* bp = Bl + (size_t)(bn + r) * RDIM;  // Bl (4096,16) fp32
        u16* d = eB + r * EXTS;
#pragma unroll
        for (int j = 0; j < RDIM; ++j) d[j] = f2bf(bp[j]);
        d[16] = f2bf(bias[bn + r]);
#pragma unroll
        for (int j = 17; j < 32; ++j) d[j] = 0;
    }
}

// ---------------------------------------------------------------------------
// Kernel 2 (path A): m97-style + XOR chunk swizzle + ext-tile LDS overlay.
// LDS slot (row, kc) holds global chunk (kc ^ (row&7)); readers XOR back.
// out = x @ W^T + bias + 2*(t @ Bl^T); fp32 store.
// ---------------------------------------------------------------------------
__global__ __launch_bounds__(256) void gemm_lora_kernel(
        const u16* __restrict__ x, const u16* __restrict__ W,
        const float* __restrict__ bias, const float* __restrict__ Bl,
        const float* __restrict__ t, float* __restrict__ out) {
    __shared__ __align__(16) u16 sA[BM * BK];   // 16 KB; ext-A overlay after K-loop
    __shared__ __align__(16) u16 sB[BN * BK];   // 16 KB; ext-B overlay after K-loop

    const int tid  = threadIdx.x;
    const int lane = tid & 63;
    const int wave = tid >> 6;
    const int wm   = wave >> 1;
    const int wn   = wave & 1;
    const int rl   = lane & 15;
    const int quad = lane >> 4;
    const int bm   = blockIdx.y * BM;
    const int bn   = blockIdx.x * BN;

    const u16* gA = x + (size_t)bm * KDIM;
    const u16* gB = W + (size_t)bn * KDIM;

    f32x4 acc[4][4];
#pragma unroll
    for (int i = 0; i < 4; ++i)
#pragma unroll
        for (int j = 0; j < 4; ++j)
            acc[i][j] = (f32x4){0.f, 0.f, 0.f, 0.f};

    for (int kt = 0; kt < KDIM; kt += BK) {
        // stage: chunk c=q*256+tid -> LDS offset c*16B (wave-uniform + lane*16)
        // global src chunk = kc ^ (row&7)  [the swizzle lives on the gather side]
#pragma unroll
        for (int q = 0; q < 4; ++q) {
            const int c   = q * 256 + tid;
            const int row = c >> 3;
            const int kc  = (c & 7) ^ (row & 7);
            __builtin_amdgcn_global_load_lds(
                (const GLOBAL_AS uint32_t*)(gA + (size_t)row * KDIM + kt + kc * 8),
                (LDS_AS uint32_t*)(sA + c * 8), 16, 0, 0);
            __builtin_amdgcn_global_load_lds(
                (const GLOBAL_AS uint32_t*)(gB + (size_t)row * KDIM + kt + kc * 8),
                (LDS_AS uint32_t*)(sB + c * 8), 16, 0, 0);
        }
        __syncthreads();   // drains vmcnt(0): tiles resident

#pragma unroll
        for (int kk = 0; kk < 2; ++kk) {
            const int lc = kk * 4 + quad;            // logical chunk 0..7
            bf16x8 af[4], bfv[4];
#pragma unroll
            for (int i = 0; i < 4; ++i) {
                const int ra = wm * 64 + i * 16 + rl;
                const int rb = wn * 64 + i * 16 + rl;
                af[i]  = *(const bf16x8*)(sA + ra * BK + (lc ^ (ra & 7)) * 8);
                bfv[i] = *(const bf16x8*)(sB + rb * BK + (lc ^ (rb & 7)) * 8);
            }
#pragma unroll
            for (int i = 0; i < 4; ++i)
#pragma unroll
                for (int j = 0; j < 4; ++j)
                    acc[i][j] = __builtin_amdgcn_mfma_f32_16x16x32_bf16(
                        af[i], bfv[j], acc[i][j], 0, 0, 0);
        }
        __syncthreads();   // all waves done reading before next overwrite
    }

    // overlay ext tiles into sA/sB (K-loop done; last barrier passed)
    stage_ext(tid, bm, bn, t, bias, Bl, sA, sB);
    __syncthreads();

    // extension K-step (bias + LoRA)
    {
        const int ko = quad * 8;
        bf16x8 af[4], bfv[4];
#pragma unroll
        for (int i = 0; i < 4; ++i) {
            af[i]  = *(const bf16x8*)(sA + (wm * 64 + i * 16 + rl) * EXTS + ko);
            bfv[i] = *(const bf16x8*)(sB + (wn * 64 + i * 16 + rl) * EXTS + ko);
        }
#pragma unroll
        for (int i = 0; i < 4; ++i)
#pragma unroll
            for (int j = 0; j < 4; ++j)
                acc[i][j] = __builtin_amdgcn_mfma_f32_16x16x32_bf16(
                    af[i], bfv[j], acc[i][j], 0, 0, 0);
    }

    // store fp32: C/D col=lane&15, row=quad*4+v
#pragma unroll
    for (int i = 0; i < 4; ++i) {
        const int grow = bm + wm * 64 + i * 16 + quad * 4;
#pragma unroll
        for (int j = 0; j < 4; ++j) {
            const int gcol = bn + wn * 64 + j * 16 + rl;
#pragma unroll
            for (int v = 0; v < 4; ++v)
                out[(size_t)(grow + v) * NDIM + gcol] = acc[i][j][v];
        }
    }
}

// ---------------------------------------------------------------------------
// Kernel 2 (path B fallback, unchanged m93-style): fp32 x/W, inline cvt
// ---------------------------------------------------------------------------
__global__ __launch_bounds__(256) void gemm_lora_inline_kernel(
        const float* __restrict__ x, const float* __restrict__ W,
        const float* __restrict__ bias, const float* __restrict__ Bl,
        const float* __restrict__ t, float* __restrict__ out) {
    __shared__ __align__(16) u16 sA[BM * BK];
    __shared__ __align__(16) u16 sB[BN * BK];
    __shared__ __align__(16) u16 sAe[BM * EXTS];
    __shared__ __align__(16) u16 sBe[BN * EXTS];

    const int tid  = threadIdx.x;
    const int lane = tid & 63;
    const int wave = tid >> 6;
    const int wm   = wave >> 1;
    const int wn   = wave & 1;
    const int rl   = lane & 15;
    const int quad = lane >> 4;
    const int bm   = blockIdx.y * BM;
    const int bn   = blockIdx.x * BN;

    stage_ext(tid, bm, bn, t, bias, Bl, sAe, sBe);

    const float* gA = x + (size_t)bm * KDIM;
    const float* gB = W + (size_t)bn * KDIM;

    const int row0 = tid >> 3;
    const int kc0  = tid & 7;

    f32x4 acc[4][4];
#pragma unroll
    for (int i = 0; i < 4; ++i)
#pragma unroll
        for (int j = 0; j < 4; ++j)
            acc[i][j] = (f32x4){0.f, 0.f, 0.f, 0.f};

    for (int kt = 0; kt < KDIM; kt += BK) {
        u16x8 ra[4], rb[4];
#pragma unroll
        for (int q = 0; q < 4; ++q) {
            const int row = q * 32 + row0;
            const int kc  = kc0 ^ (row & 7);
            const size_t base = (size_t)row * KDIM + kt + kc * 8;
            f32x4 a0 = *(const f32x4*)(gA + base), a1 = *(const f32x4*)(gA + base + 4);
            f32x4 b0 = *(const f32x4*)(gB + base), b1 = *(const f32x4*)(gB + base + 4);
#pragma unroll
            for (int j = 0; j < 4; ++j) {
                ra[q][j] = f2bf(a0[j]); ra[q][j + 4] = f2bf(a1[j]);
                rb[q][j] = f2bf(b0[j]); rb[q][j + 4] = f2bf(b1[j]);
            }
        }
        __syncthreads();
#pragma unroll
        for (int q = 0; q < 4; ++q) {
            const int c = q * 256 + tid;
            *(u16x8*)(sA + c * 8) = ra[q];
            *(u16x8*)(sB + c * 8) = rb[q];
        }
        __syncthreads();

#pragma unroll
        for (int kk = 0; kk < 2; ++kk) {
            const int lc = kk * 4 + quad;
            bf16x8 af[4], bfv[4];
#pragma unroll
            for (int i = 0; i < 4; ++i) {
                const int rra = wm * 64 + i * 16 + rl;
                const int rrb = wn * 64 + i * 16 + rl;
                af[i]  = *(const bf16x8*)(sA + rra * BK + (lc ^ (rra & 7)) * 8);
                bfv[i] = *(const bf16x8*)(sB + rrb * BK + (lc ^ (rrb & 7)) * 8);
            }
#pragma unroll
            for (int i = 0; i < 4; ++i)
#pragma unroll
                for (int j = 0; j < 4; ++j)
                    acc[i][j] = __builtin_amdgcn_mfma_f32_16x16x32_bf16(
                        af[i], bfv[j], acc[i][j], 0, 0, 0);
        }
    }

    {
        const int ko = quad * 8;
        bf16x8 af[4], bfv[4];
#pragma unroll
        for (int i = 0; i < 4; ++i) {
            af[i]  = *(const bf16x8*)(sAe + (wm * 64 + i * 16 + rl) * EXTS + ko);
            bfv[i] = *(const bf16x8*)(sBe + (wn * 64 + i * 16 + rl) * EXTS + ko);
        }
#pragma unroll
        for (int i = 0; i < 4; ++i)
#pragma unroll
            for (int j = 0; j < 4; ++j)
                acc[i][j] = __builtin_amdgcn_mfma_f32_16x16x32_bf16(
                    af[i], bfv[j], acc[i][j], 0, 0, 0);
    }

#pragma unroll
    for (int i = 0; i < 4; ++i) {
        const int grow = bm + wm * 64 + i * 16 + quad * 4;
#pragma unroll
        for (int j = 0; j < 4; ++j) {
            const int gcol = bn + wn * 64 + j * 16 + rl;
#pragma unroll
            for (int v = 0; v < 4; ++v)
                out[(size_t)(grow + v) * NDIM + gcol] = acc[i][j][v];
        }
    }
}

// ---------------------------------------------------------------------------
extern "C" void kernel_launch(void* const* d_in, const int* in_sizes, int n_in,
                              void* d_out, int out_size, void* d_ws, size_t ws_size,
                              hipStream_t stream) {
    const float* x  = (const float*)d_in[0];  // (8192, 4096) fp32
    const float* W  = (const float*)d_in[1];  // (4096, 4096) fp32
    const float* b  = (const float*)d_in[2];  // (4096,)      fp32
    const float* A  = (const float*)d_in[3];  // (16, 4096)   fp32
    const float* Bl = (const float*)d_in[4];  // (4096, 16)   fp32
    float* out = (float*)d_out;               // (8192, 4096) fp32
    char* ws = (char*)d_ws;

    dim3 grid(NDIM / BN, MDIM / BM);  // (32, 64)

    if (ws_size >= WS_NEED) {
        u16*   xbf = (u16*)(ws + XBF_OFF);
        u16*   Wbf = (u16*)(ws + WBF_OFF);
        u16*   Abf = (u16*)(ws + ABF_OFF);
        float* t   = (float*)(ws + T_OFF);

        cvt_all_kernel<<<4096, 256, 0, stream>>>(x, W, A, xbf, Wbf, Abf);
        lora_t_kernel<<<128, 256, 0, stream>>>(xbf, Abf, t);
        gemm_lora_kernel<<<grid, 256, 0, stream>>>(xbf, Wbf, b, Bl, t, out);
    } else {
        float* t = (float*)ws;
        lora_t_inline_kernel<<<128, 256, 0, stream>>>(x, A, t);
        gemm_lora_inline_kernel<<<grid, 256, 0, stream>>>(x, W, b, Bl, t, out);
    }
}

// Round 5
// 591.245 us; speedup vs baseline: 1.1496x; 1.0843x over previous
//
#include <hip/hip_runtime.h>
#include <stdint.h>

typedef unsigned short u16;
typedef __bf16 bf16x8 __attribute__((ext_vector_type(8)));
typedef u16   u16x8  __attribute__((ext_vector_type(8)));
typedef float f32x4  __attribute__((ext_vector_type(4)));
typedef float f32x16 __attribute__((ext_vector_type(16)));

#define GLOBAL_AS __attribute__((address_space(1)))
#define LDS_AS __attribute__((address_space(3)))

#define MDIM 8192
#define NDIM 4096
#define KDIM 4096
#define RDIM 16

#define BM 128
#define BN 128
#define BK 64
#define EXTS 40   // path-B ext-tile row stride in u16

// ws layout (path A): [x_bf16 64MB][W_bf16 32MB][A_bf16 128KB][t fp32 512KB]
#define XBF_OFF 0
#define WBF_OFF (MDIM * KDIM * 2)
#define ABF_OFF (WBF_OFF + NDIM * KDIM * 2)
#define T_OFF   (ABF_OFF + RDIM * KDIM * 2)
#define WS_NEED ((size_t)T_OFF + MDIM * RDIM * 4)

#define XN8 (MDIM * KDIM / 8)
#define WN8 (NDIM * KDIM / 8)
#define AN8 (RDIM * KDIM / 8)

__device__ __forceinline__ u16 f2bf(float f) {
    union { float f; uint32_t u; } un;
    un.f = f;
    uint32_t u = un.u;
    u += 0x7FFFu + ((u >> 16) & 1u);   // round-to-nearest-even
    return (u16)(u >> 16);
}

__device__ __forceinline__ void cvt8(const float* __restrict__ p, u16* __restrict__ d) {
    f32x4 a = *(const f32x4*)p;
    f32x4 b = *(const f32x4*)(p + 4);
    u16x8 o;
    o[0] = f2bf(a[0]); o[1] = f2bf(a[1]); o[2] = f2bf(a[2]); o[3] = f2bf(a[3]);
    o[4] = f2bf(b[0]); o[5] = f2bf(b[1]); o[6] = f2bf(b[2]); o[7] = f2bf(b[3]);
    *(u16x8*)d = o;
}

// ---------------------------------------------------------------------------
// fused fp32->bf16 convert for x, W, A (one launch)
// ---------------------------------------------------------------------------
__global__ __launch_bounds__(256) void cvt_all_kernel(
        const float* __restrict__ x, const float* __restrict__ W,
        const float* __restrict__ A,
        u16* __restrict__ xbf, u16* __restrict__ Wbf, u16* __restrict__ Abf) {
    const int total = XN8 + WN8 + AN8;
    int i = blockIdx.x * blockDim.x + threadIdx.x;
    const int stride = gridDim.x * blockDim.x;
    for (; i < total; i += stride) {
        if (i < XN8) {
            cvt8(x + (size_t)i * 8, xbf + (size_t)i * 8);
        } else if (i < XN8 + WN8) {
            const int j = i - XN8;
            cvt8(W + (size_t)j * 8, Wbf + (size_t)j * 8);
        } else {
            const int j = i - XN8 - WN8;
            cvt8(A + (size_t)j * 8, Abf + (size_t)j * 8);
        }
    }
}

// ---------------------------------------------------------------------------
// Kernel 1: t[n][r] = sum_i x[n,i]*A[r,i], bf16 in / fp32 out (16x16x32)
// ---------------------------------------------------------------------------
__global__ __launch_bounds__(256) void lora_t_kernel(
        const u16* __restrict__ x, const u16* __restrict__ A,
        float* __restrict__ t) {
    const int wave = threadIdx.x >> 6;
    const int lane = threadIdx.x & 63;
    const int rl   = lane & 15;
    const int quad = lane >> 4;
    const int m0   = (blockIdx.x * 4 + wave) * 16;

    const u16* xp = x + (size_t)(m0 + rl) * KDIM + quad * 8;  // A-op: x[m][k]
    const u16* ap = A + (size_t)rl * KDIM + quad * 8;         // B-op: B[k][n]=A[n][k]

    f32x4 acc = {0.f, 0.f, 0.f, 0.f};
#pragma unroll 8
    for (int k = 0; k < KDIM; k += 32) {
        bf16x8 av = *(const bf16x8*)(xp + k);
        bf16x8 bv = *(const bf16x8*)(ap + k);
        acc = __builtin_amdgcn_mfma_f32_16x16x32_bf16(av, bv, acc, 0, 0, 0);
    }
    const int orow = m0 + quad * 4;   // C/D: col=lane&15, row=quad*4+v
#pragma unroll
    for (int v = 0; v < 4; ++v)
        t[(size_t)(orow + v) * RDIM + rl] = acc[v];
}

// Kernel 1 (path B): fp32 inputs, inline cvt
__global__ __launch_bounds__(256) void lora_t_inline_kernel(
        const float* __restrict__ x, const float* __restrict__ A,
        float* __restrict__ t) {
    const int wave = threadIdx.x >> 6;
    const int lane = threadIdx.x & 63;
    const int rl   = lane & 15;
    const int quad = lane >> 4;
    const int m0   = (blockIdx.x * 4 + wave) * 16;

    const float* xp = x + (size_t)(m0 + rl) * KDIM + quad * 8;
    const float* ap = A + (size_t)rl * KDIM + quad * 8;

    f32x4 acc = {0.f, 0.f, 0.f, 0.f};
    for (int k = 0; k < KDIM; k += 32) {
        f32x4 a0 = *(const f32x4*)(xp + k), a1 = *(const f32x4*)(xp + k + 4);
        f32x4 b0 = *(const f32x4*)(ap + k), b1 = *(const f32x4*)(ap + k + 4);
        u16x8 av, bv;
#pragma unroll
        for (int j = 0; j < 4; ++j) {
            av[j] = f2bf(a0[j]); av[j + 4] = f2bf(a1[j]);
            bv[j] = f2bf(b0[j]); bv[j + 4] = f2bf(b1[j]);
        }
        acc = __builtin_amdgcn_mfma_f32_16x16x32_bf16(
            (bf16x8)av, (bf16x8)bv, acc, 0, 0, 0);
    }
    const int orow = m0 + quad * 4;
#pragma unroll
    for (int v = 0; v < 4; ++v)
        t[(size_t)(orow + v) * RDIM + rl] = acc[v];
}

// ---------------------------------------------------------------------------
// Kernel 2 (path A): 128x128 tile, 32x32x16 MFMA (2x2 per wave), XOR swizzle,
// global_load_lds width=16. LoRA ext = one K=16 MFMA; bias in epilogue.
// out = x @ W^T + bias + 2*(t @ Bl^T); fp32 store.
// ---------------------------------------------------------------------------
__global__ __launch_bounds__(256) void gemm_lora_kernel(
        const u16* __restrict__ x, const u16* __restrict__ W,
        const float* __restrict__ bias, const float* __restrict__ Bl,
        const float* __restrict__ t, float* __restrict__ out) {
    __shared__ __align__(16) u16 sA[BM * BK];   // 16 KB; ext-A overlay after K-loop
    __shared__ __align__(16) u16 sB[BN * BK];   // 16 KB; ext-B overlay after K-loop

    const int tid  = threadIdx.x;
    const int lane = tid & 63;
    const int wave = tid >> 6;
    const int wm   = wave >> 1;       // 2x2 wave grid; wave tile 64x64
    const int wn   = wave & 1;
    const int ml   = lane & 31;       // 32x32 operand: outdim = lane&31
    const int half = lane >> 5;       // k = half*8 + j
    const int bm   = blockIdx.y * BM;
    const int bn   = blockIdx.x * BN;

    const u16* gA = x + (size_t)bm * KDIM;
    const u16* gB = W + (size_t)bn * KDIM;

    f32x16 acc[2][2];
#pragma unroll
    for (int i = 0; i < 2; ++i)
#pragma unroll
        for (int j = 0; j < 2; ++j)
            acc[i][j] = (f32x16)(0.f);

    for (int kt = 0; kt < KDIM; kt += BK) {
        // stage: chunk c=q*256+tid -> LDS offset c*16B (wave-uniform + lane*16)
        // global src chunk = kc ^ (row&7)  [swizzle on the gather side]
#pragma unroll
        for (int q = 0; q < 4; ++q) {
            const int c   = q * 256 + tid;
            const int row = c >> 3;
            const int kc  = (c & 7) ^ (row & 7);
            __builtin_amdgcn_global_load_lds(
                (const GLOBAL_AS uint32_t*)(gA + (size_t)row * KDIM + kt + kc * 8),
                (LDS_AS uint32_t*)(sA + c * 8), 16, 0, 0);
            __builtin_amdgcn_global_load_lds(
                (const GLOBAL_AS uint32_t*)(gB + (size_t)row * KDIM + kt + kc * 8),
                (LDS_AS uint32_t*)(sB + c * 8), 16, 0, 0);
        }
        __syncthreads();   // drains vmcnt(0): tiles resident

        // 4 k-steps of 16; per step: 4 ds_read_b128 + 4 MFMA(32x32x16)
#pragma unroll
        for (int kk = 0; kk < 4; ++kk) {
            const int lc = kk * 2 + half;            // logical chunk 0..7
            bf16x8 af[2], bfv[2];
#pragma unroll
            for (int i = 0; i < 2; ++i) {
                const int ra = wm * 64 + i * 32 + ml;
                const int rb = wn * 64 + i * 32 + ml;
                af[i]  = *(const bf16x8*)(sA + ra * BK + (lc ^ (ra & 7)) * 8);
                bfv[i] = *(const bf16x8*)(sB + rb * BK + (lc ^ (rb & 7)) * 8);
            }
#pragma unroll
            for (int i = 0; i < 2; ++i)
#pragma unroll
                for (int j = 0; j < 2; ++j)
                    acc[i][j] = __builtin_amdgcn_mfma_f32_32x32x16_bf16(
                        af[i], bfv[j], acc[i][j], 0, 0, 0);
        }
        __syncthreads();   // all waves done reading before next overwrite
    }

    // overlay ext tiles (stride 16 u16): sA[r][k]=2t, sB[c][k]=Bl
    if (tid < 128) {
        const float* tp = t + (size_t)(bm + tid) * RDIM;
        u16* d = sA + tid * 16;
#pragma unroll
        for (int j = 0; j < RDIM; ++j) d[j] = f2bf(2.0f * tp[j]);
    } else {
        const int r = tid - 128;
        const float* bp = Bl + (size_t)(bn + r) * RDIM;
        u16* d = sB + r * 16;
#pragma unroll
        for (int j = 0; j < RDIM; ++j) d[j] = f2bf(bp[j]);
    }
    __syncthreads();

    // LoRA extension K-step: K=16 exactly = RDIM, one MFMA per acc tile
    {
        bf16x8 ae[2], be[2];
#pragma unroll
        for (int i = 0; i < 2; ++i) {
            ae[i] = *(const bf16x8*)(sA + (wm * 64 + i * 32 + ml) * 16 + half * 8);
            be[i] = *(const bf16x8*)(sB + (wn * 64 + i * 32 + ml) * 16 + half * 8);
        }
#pragma unroll
        for (int i = 0; i < 2; ++i)
#pragma unroll
            for (int j = 0; j < 2; ++j)
                acc[i][j] = __builtin_amdgcn_mfma_f32_32x32x16_bf16(
                    ae[i], be[j], acc[i][j], 0, 0, 0);
    }

    // epilogue: + bias, store fp32.
    // C/D: col=lane&31, row=(reg&3)+8*(reg>>2)+4*(lane>>5)  [m74/m101]
    float bv[2];
#pragma unroll
    for (int j = 0; j < 2; ++j)
        bv[j] = bias[bn + wn * 64 + j * 32 + ml];
#pragma unroll
    for (int i = 0; i < 2; ++i) {
        const int rbase = bm + wm * 64 + i * 32 + 4 * half;
#pragma unroll
        for (int j = 0; j < 2; ++j) {
            const int gcol = bn + wn * 64 + j * 32 + ml;
#pragma unroll
            for (int reg = 0; reg < 16; ++reg) {
                const int grow = rbase + (reg & 3) + 8 * (reg >> 2);
                out[(size_t)grow * NDIM + gcol] = acc[i][j][reg] + bv[j];
            }
        }
    }
}

// ---------------------------------------------------------------------------
// Path B fallback (unchanged R4 16x16 m93-style): fp32 x/W, inline cvt
// ---------------------------------------------------------------------------
__device__ __forceinline__ void stage_ext_b(
        int tid, int bm, int bn,
        const float* __restrict__ t, const float* __restrict__ bias,
        const float* __restrict__ Bl, u16* eA, u16* eB) {
    if (tid < 128) {
        const int r = tid;
        const float* tp = t + (size_t)(bm + r) * RDIM;
        u16* d = eA + r * EXTS;
#pragma unroll
        for (int j = 0; j < RDIM; ++j) d[j] = f2bf(2.0f * tp[j]);
        d[16] = 0x3F80;                                  // 1.0 bf16
#pragma unroll
        for (int j = 17; j < 32; ++j) d[j] = 0;
    } else {
        const int r = tid - 128;
        const float* bp = Bl + (size_t)(bn + r) * RDIM;
        u16* d = eB + r * EXTS;
#pragma unroll
        for (int j = 0; j < RDIM; ++j) d[j] = f2bf(bp[j]);
        d[16] = f2bf(bias[bn + r]);
#pragma unroll
        for (int j = 17; j < 32; ++j) d[j] = 0;
    }
}

__global__ __launch_bounds__(256) void gemm_lora_inline_kernel(
        const float* __restrict__ x, const float* __restrict__ W,
        const float* __restrict__ bias, const float* __restrict__ Bl,
        const float* __restrict__ t, float* __restrict__ out) {
    __shared__ __align__(16) u16 sA[BM * BK];
    __shared__ __align__(16) u16 sB[BN * BK];
    __shared__ __align__(16) u16 sAe[BM * EXTS];
    __shared__ __align__(16) u16 sBe[BN * EXTS];

    const int tid  = threadIdx.x;
    const int lane = tid & 63;
    const int wave = tid >> 6;
    const int wm   = wave >> 1;
    const int wn   = wave & 1;
    const int rl   = lane & 15;
    const int quad = lane >> 4;
    const int bm   = blockIdx.y * BM;
    const int bn   = blockIdx.x * BN;

    stage_ext_b(tid, bm, bn, t, bias, Bl, sAe, sBe);

    const float* gA = x + (size_t)bm * KDIM;
    const float* gB = W + (size_t)bn * KDIM;

    const int row0 = tid >> 3;
    const int kc0  = tid & 7;

    f32x4 acc[4][4];
#pragma unroll
    for (int i = 0; i < 4; ++i)
#pragma unroll
        for (int j = 0; j < 4; ++j)
            acc[i][j] = (f32x4){0.f, 0.f, 0.f, 0.f};

    for (int kt = 0; kt < KDIM; kt += BK) {
        u16x8 ra[4], rb[4];
#pragma unroll
        for (int q = 0; q < 4; ++q) {
            const int row = q * 32 + row0;
            const int kc  = kc0 ^ (row & 7);
            const size_t base = (size_t)row * KDIM + kt + kc * 8;
            f32x4 a0 = *(const f32x4*)(gA + base), a1 = *(const f32x4*)(gA + base + 4);
            f32x4 b0 = *(const f32x4*)(gB + base), b1 = *(const f32x4*)(gB + base + 4);
#pragma unroll
            for (int j = 0; j < 4; ++j) {
                ra[q][j] = f2bf(a0[j]); ra[q][j + 4] = f2bf(a1[j]);
                rb[q][j] = f2bf(b0[j]); rb[q][j + 4] = f2bf(b1[j]);
            }
        }
        __syncthreads();
#pragma unroll
        for (int q = 0; q < 4; ++q) {
            const int c = q * 256 + tid;
            *(u16x8*)(sA + c * 8) = ra[q];
            *(u16x8*)(sB + c * 8) = rb[q];
        }
        __syncthreads();

#pragma unroll
        for (int kk = 0; kk < 2; ++kk) {
            const int lc = kk * 4 + quad;
            bf16x8 af[4], bfv[4];
#pragma unroll
            for (int i = 0; i < 4; ++i) {
                const int rra = wm * 64 + i * 16 + rl;
                const int rrb = wn * 64 + i * 16 + rl;
                af[i]  = *(const bf16x8*)(sA + rra * BK + (lc ^ (rra & 7)) * 8);
                bfv[i] = *(const bf16x8*)(sB + rrb * BK + (lc ^ (rrb & 7)) * 8);
            }
#pragma unroll
            for (int i = 0; i < 4; ++i)
#pragma unroll
                for (int j = 0; j < 4; ++j)
                    acc[i][j] = __builtin_amdgcn_mfma_f32_16x16x32_bf16(
                        af[i], bfv[j], acc[i][j], 0, 0, 0);
        }
    }

    {
        const int ko = quad * 8;
        bf16x8 af[4], bfv[4];
#pragma unroll
        for (int i = 0; i < 4; ++i) {
            af[i]  = *(const bf16x8*)(sAe + (wm * 64 + i * 16 + rl) * EXTS + ko);
            bfv[i] = *(const bf16x8*)(sBe + (wn * 64 + i * 16 + rl) * EXTS + ko);
        }
#pragma unroll
        for (int i = 0; i < 4; ++i)
#pragma unroll
            for (int j = 0; j < 4; ++j)
                acc[i][j] = __builtin_amdgcn_mfma_f32_16x16x32_bf16(
                    af[i], bfv[j], acc[i][j], 0, 0, 0);
    }

#pragma unroll
    for (int i = 0; i < 4; ++i) {
        const int grow = bm + wm * 64 + i * 16 + quad * 4;
#pragma unroll
        for (int j = 0; j < 4; ++j) {
            const int gcol = bn + wn * 64 + j * 16 + rl;
#pragma unroll
            for (int v = 0; v < 4; ++v)
                out[(size_t)(grow + v) * NDIM + gcol] = acc[i][j][v];
        }
    }
}

// ---------------------------------------------------------------------------
extern "C" void kernel_launch(void* const* d_in, const int* in_sizes, int n_in,
                              void* d_out, int out_size, void* d_ws, size_t ws_size,
                              hipStream_t stream) {
    const float* x  = (const float*)d_in[0];  // (8192, 4096) fp32
    const float* W  = (const float*)d_in[1];  // (4096, 4096) fp32
    const float* b  = (const float*)d_in[2];  // (4096,)      fp32
    const float* A  = (const float*)d_in[3];  // (16, 4096)   fp32
    const float* Bl = (const float*)d_in[4];  // (4096, 16)   fp32
    float* out = (float*)d_out;               // (8192, 4096) fp32
    char* ws = (char*)d_ws;

    dim3 grid(NDIM / BN, MDIM / BM);  // (32, 64)

    if (ws_size >= WS_NEED) {
        u16*   xbf = (u16*)(ws + XBF_OFF);
        u16*   Wbf = (u16*)(ws + WBF_OFF);
        u16*   Abf = (u16*)(ws + ABF_OFF);
        float* t   = (float*)(ws + T_OFF);

        cvt_all_kernel<<<4096, 256, 0, stream>>>(x, W, A, xbf, Wbf, Abf);
        lora_t_kernel<<<128, 256, 0, stream>>>(xbf, Abf, t);
        gemm_lora_kernel<<<grid, 256, 0, stream>>>(xbf, Wbf, b, Bl, t, out);
    } else {
        float* t = (float*)ws;
        lora_t_inline_kernel<<<128, 256, 0, stream>>>(x, A, t);
        gemm_lora_inline_kernel<<<grid, 256, 0, stream>>>(x, W, b, Bl, t, out);
    }
}